// Round 1
// baseline (234.931 us; speedup 1.0000x reference)
//
#include <hip/hip_runtime.h>

// IndRNN forward: proj = x @ W + b  (M=B*T, K=D, N=U), then
// h_t = relu(proj_t + h_{t-1} * clip(u,0,1)) scanned over T.
// Round 0: fp32 SGEMM into d_out, then in-place scan over d_out.

#define BM 128
#define BN 128
#define BK 8

__global__ __launch_bounds__(256) void indrnn_gemm_bias(
    const float* __restrict__ A,    // x  [M, K]
    const float* __restrict__ Bm,   // W  [K, N]
    const float* __restrict__ bias, // b  [N]
    float* __restrict__ C,          // proj out [M, N]
    int M, int N, int K)
{
    __shared__ float As[BK][BM];
    __shared__ float Bs[BK][BN];

    const int tid  = threadIdx.x;
    const int row0 = blockIdx.x * BM;
    const int col0 = blockIdx.y * BN;

    const int tx = tid & 15;   // 0..15 -> column groups
    const int ty = tid >> 4;   // 0..15 -> row groups

    float acc[8][8];
#pragma unroll
    for (int i = 0; i < 8; ++i)
#pragma unroll
        for (int j = 0; j < 8; ++j) acc[i][j] = 0.0f;

    // A staging: each thread loads one float4 along K; m = tid>>1, k4 = (tid&1)*4
    const int am = tid >> 1;
    const int ak = (tid & 1) * 4;
    // B staging: k = tid>>5 (0..7), n4 = (tid&31)*4
    const int bk = tid >> 5;
    const int bn = (tid & 31) * 4;

    const float* Aptr = A + (long)(row0 + am) * K + ak;
    const float* Bptr = Bm + (long)bk * N + col0 + bn;

    for (int kt = 0; kt < K; kt += BK) {
        float4 av = *(const float4*)(Aptr + kt);
        float4 bv = *(const float4*)(Bptr + (long)kt * N);
        // transpose A tile into As[k][m]
        As[ak + 0][am] = av.x;
        As[ak + 1][am] = av.y;
        As[ak + 2][am] = av.z;
        As[ak + 3][am] = av.w;
        *(float4*)&Bs[bk][bn] = bv;
        __syncthreads();
#pragma unroll
        for (int k = 0; k < BK; ++k) {
            float4 a0 = *(const float4*)&As[k][ty * 4];
            float4 a1 = *(const float4*)&As[k][64 + ty * 4];
            float4 b0 = *(const float4*)&Bs[k][tx * 4];
            float4 b1 = *(const float4*)&Bs[k][64 + tx * 4];
            float a[8] = {a0.x, a0.y, a0.z, a0.w, a1.x, a1.y, a1.z, a1.w};
            float b[8] = {b0.x, b0.y, b0.z, b0.w, b1.x, b1.y, b1.z, b1.w};
#pragma unroll
            for (int i = 0; i < 8; ++i)
#pragma unroll
                for (int j = 0; j < 8; ++j)
                    acc[i][j] = fmaf(a[i], b[j], acc[i][j]);
        }
        __syncthreads();
    }

    // bias for this thread's 8 columns
    float bb[8];
#pragma unroll
    for (int j = 0; j < 4; ++j) {
        bb[j]     = bias[col0 + tx * 4 + j];
        bb[j + 4] = bias[col0 + 64 + tx * 4 + j];
    }

#pragma unroll
    for (int i = 0; i < 8; ++i) {
        const int r = (i < 4) ? (ty * 4 + i) : (64 + ty * 4 + (i - 4));
        float* crow = C + (long)(row0 + r) * N + col0;
        float4 v0, v1;
        v0.x = acc[i][0] + bb[0];
        v0.y = acc[i][1] + bb[1];
        v0.z = acc[i][2] + bb[2];
        v0.w = acc[i][3] + bb[3];
        v1.x = acc[i][4] + bb[4];
        v1.y = acc[i][5] + bb[5];
        v1.z = acc[i][6] + bb[6];
        v1.w = acc[i][7] + bb[7];
        *(float4*)(crow + tx * 4)      = v0;
        *(float4*)(crow + 64 + tx * 4) = v1;
    }
}

#define SCAN_UNROLL 16

__global__ __launch_bounds__(256) void indrnn_scan(
    float* __restrict__ out,      // [B, T, U] : proj in, h out (in place)
    const float* __restrict__ h0, // [B, U]
    const float* __restrict__ u,  // [U]
    int B, int T, int U)
{
    const int nvec = U >> 2;                             // float4 groups per batch
    const int idx  = blockIdx.x * blockDim.x + threadIdx.x;
    if (idx >= B * nvec) return;
    const int b  = idx / nvec;
    const int u4 = idx - b * nvec;

    float4 ur = *(const float4*)(u + u4 * 4);
    float4 uc;
    uc.x = fminf(fmaxf(ur.x, 0.0f), 1.0f);
    uc.y = fminf(fmaxf(ur.y, 0.0f), 1.0f);
    uc.z = fminf(fmaxf(ur.z, 0.0f), 1.0f);
    uc.w = fminf(fmaxf(ur.w, 0.0f), 1.0f);

    float4 h = *(const float4*)(h0 + (long)b * U + u4 * 4);

    float* p = out + (long)b * T * U + u4 * 4;

    for (int t = 0; t < T; t += SCAN_UNROLL) {
        float4 pv[SCAN_UNROLL];
#pragma unroll
        for (int i = 0; i < SCAN_UNROLL; ++i)
            pv[i] = *(const float4*)(p + (long)(t + i) * U);
#pragma unroll
        for (int i = 0; i < SCAN_UNROLL; ++i) {
            h.x = fmaxf(fmaf(h.x, uc.x, pv[i].x), 0.0f);
            h.y = fmaxf(fmaf(h.y, uc.y, pv[i].y), 0.0f);
            h.z = fmaxf(fmaf(h.z, uc.z, pv[i].z), 0.0f);
            h.w = fmaxf(fmaf(h.w, uc.w, pv[i].w), 0.0f);
            *(float4*)(p + (long)(t + i) * U) = h;
        }
    }
}

extern "C" void kernel_launch(void* const* d_in, const int* in_sizes, int n_in,
                              void* d_out, int out_size, void* d_ws, size_t ws_size,
                              hipStream_t stream) {
    const float* x  = (const float*)d_in[0]; // [B,T,D]
    const float* h0 = (const float*)d_in[1]; // [B,U]
    const float* W  = (const float*)d_in[2]; // [D,U]
    const float* u  = (const float*)d_in[3]; // [U]
    const float* b  = (const float*)d_in[4]; // [U]
    float* out = (float*)d_out;              // [B,T,U]

    const int U = in_sizes[3];
    const int B = in_sizes[1] / U;
    const int D = in_sizes[2] / U;
    const int T = in_sizes[0] / (B * D);
    const int M = B * T;

    // proj = x @ W + b  -> out
    dim3 ggrid(M / BM, U / BN);
    indrnn_gemm_bias<<<ggrid, 256, 0, stream>>>(x, W, b, out, M, U, D);

    // in-place scan over T
    const int nthreads = B * (U / 4);
    indrnn_scan<<<(nthreads + 255) / 256, 256, 0, stream>>>(out, h0, u, B, T, U);
}

// Round 2
// 138.358 us; speedup vs baseline: 1.6980x; 1.6980x over previous
//
#include <hip/hip_runtime.h>

// IndRNN forward: proj = x @ W + b  (M=B*T, K=D, N=U), then
// h_t = relu(proj_t + h_{t-1} * clip(u,0,1)) scanned over T.
// R1: bf16 MFMA GEMM (m97 structure: global_load_lds w=16, 128x128 tile,
//     XOR-swizzled LDS chunks) + restructured scan (scalar/thread, 512 waves,
//     batched loads/stores). fp32 GEMM fallback if ws too small.

// ---------------------------------------------------------------- utilities
__device__ __forceinline__ unsigned short f2bf(float f) {
    unsigned int u = __float_as_uint(f);
    unsigned int r = (u + 0x7FFF + ((u >> 16) & 1)) >> 16;  // RNE
    return (unsigned short)r;
}

typedef __bf16 bf16x8 __attribute__((ext_vector_type(8)));
typedef float f32x4 __attribute__((ext_vector_type(4)));

typedef const unsigned char __attribute__((address_space(1))) gc_t;
typedef unsigned char __attribute__((address_space(3))) lds_t;

__device__ __forceinline__ void gl_lds16(const void* g, void* l) {
    __builtin_amdgcn_global_load_lds((gc_t*)g, (lds_t*)l, 16, 0, 0);
}

// ------------------------------------------------------------ conversion
// x [M,K] fp32 -> bf16, 4 elems/thread
__global__ __launch_bounds__(256) void conv_x(
    const float* __restrict__ x, unsigned short* __restrict__ xb, int n4)
{
    int i = blockIdx.x * blockDim.x + threadIdx.x;
    if (i >= n4) return;
    float4 v = *(const float4*)(x + (long)i * 4);
    ushort4 o;
    o.x = f2bf(v.x); o.y = f2bf(v.y); o.z = f2bf(v.z); o.w = f2bf(v.w);
    *(ushort4*)(xb + (long)i * 4) = o;
}

// W [K,N] fp32 -> Wt [N,K] bf16 (transpose). thread -> (n, k4)
__global__ __launch_bounds__(256) void conv_wt(
    const float* __restrict__ W, unsigned short* __restrict__ Wt, int K, int N)
{
    int idx = blockIdx.x * blockDim.x + threadIdx.x;
    int kq = K >> 2;
    if (idx >= N * kq) return;
    int n = idx / kq;
    int k4 = (idx - n * kq) * 4;
    ushort4 o;
    o.x = f2bf(W[(long)(k4 + 0) * N + n]);
    o.y = f2bf(W[(long)(k4 + 1) * N + n]);
    o.z = f2bf(W[(long)(k4 + 2) * N + n]);
    o.w = f2bf(W[(long)(k4 + 3) * N + n]);
    *(ushort4*)(Wt + (long)n * K + k4) = o;
}

// ------------------------------------------------------------ MFMA GEMM
// C[M,N] = A[M,K](bf16) @ Wt[N,K]^T(bf16) + bias, fp32 out.
// 128x128 tile, BK=32, 4 waves, each wave 64x64 (4x4 MFMA 16x16x32 tiles).
#define GBM 128
#define GBN 128
#define GBK 32

__global__ __launch_bounds__(256) void gemm_mfma(
    const unsigned short* __restrict__ Ab,   // bf16 bits [M,K]
    const unsigned short* __restrict__ Btb,  // bf16 bits [N,K]
    const float* __restrict__ bias,          // [N]
    float* __restrict__ C, int M, int N, int K)
{
    __shared__ __bf16 As[GBM * GBK];
    __shared__ __bf16 Bs[GBN * GBK];

    const int tid  = threadIdx.x;
    const int lane = tid & 63;
    const int w    = tid >> 6;          // wave 0..3
    const int m    = lane & 15;
    const int quad = lane >> 4;         // 0..3
    const int row0 = blockIdx.x * GBM;
    const int col0 = blockIdx.y * GBN;

    // staging: per call a wave covers 16 rows x 64B; XOR chunk swizzle
    const int sr = lane >> 2;                          // row within 16-row chunk
    const int sg = ((lane & 3) - ((sr >> 1) & 3)) & 3; // global k-chunk fetched
    // frag read slot (inverse swizzle): slot = ((row>>1) + quad) & 3 -> ((m>>1)+quad)&3
    const int slot = (((m >> 1) & 3) + quad) & 3;

    f32x4 acc[4][4];
#pragma unroll
    for (int i = 0; i < 4; ++i)
#pragma unroll
        for (int j = 0; j < 4; ++j) acc[i][j] = (f32x4){0.f, 0.f, 0.f, 0.f};

    const int rowA_base = (w >> 1) * 64;  // wave's row quadrant
    const int colB_base = (w & 1) * 64;   // wave's col quadrant

    for (int kt = 0; kt < K; kt += GBK) {
        // stage A: wave w covers tile rows w*32 .. w*32+31 (2 calls of 16 rows)
#pragma unroll
        for (int c = 0; c < 2; ++c) {
            int rt = w * 32 + c * 16;  // tile-row base of this call
            const unsigned short* ga =
                Ab + (long)(row0 + rt + sr) * K + kt + sg * 8;
            gl_lds16(ga, (void*)(As + (rt)*GBK));
            const unsigned short* gb =
                Btb + (long)(col0 + rt + sr) * K + kt + sg * 8;
            gl_lds16(gb, (void*)(Bs + (rt)*GBK));
        }
        __syncthreads();

        bf16x8 af[4], bf[4];
#pragma unroll
        for (int i = 0; i < 4; ++i) {
            int rowA = rowA_base + i * 16 + m;
            af[i] = *(const bf16x8*)(As + rowA * GBK + slot * 8);
            int rowB = colB_base + i * 16 + m;
            bf[i] = *(const bf16x8*)(Bs + rowB * GBK + slot * 8);
        }
#pragma unroll
        for (int i = 0; i < 4; ++i)
#pragma unroll
            for (int j = 0; j < 4; ++j)
                acc[i][j] = __builtin_amdgcn_mfma_f32_16x16x32_bf16(
                    af[i], bf[j], acc[i][j], 0, 0, 0);
        __syncthreads();
    }

    // epilogue: C row = row0+rowA_base+i*16+quad*4+r, col = col0+colB_base+j*16+m
    float bb[4];
#pragma unroll
    for (int j = 0; j < 4; ++j) bb[j] = bias[col0 + colB_base + j * 16 + m];

#pragma unroll
    for (int i = 0; i < 4; ++i) {
#pragma unroll
        for (int r = 0; r < 4; ++r) {
            int row = row0 + rowA_base + i * 16 + quad * 4 + r;
            float* crow = C + (long)row * N + col0 + colB_base + m;
#pragma unroll
            for (int j = 0; j < 4; ++j)
                crow[j * 16] = acc[i][j][r] + bb[j];
        }
    }
}

// ------------------------------------------------------------ fp32 fallback GEMM
#define BM 128
#define BN 128
#define BK 8

__global__ __launch_bounds__(256) void indrnn_gemm_bias(
    const float* __restrict__ A, const float* __restrict__ Bm,
    const float* __restrict__ bias, float* __restrict__ C,
    int M, int N, int K)
{
    __shared__ float As[BK][BM];
    __shared__ float Bs[BK][BN];
    const int tid = threadIdx.x;
    const int row0 = blockIdx.x * BM, col0 = blockIdx.y * BN;
    const int tx = tid & 15, ty = tid >> 4;
    float acc[8][8];
#pragma unroll
    for (int i = 0; i < 8; ++i)
#pragma unroll
        for (int j = 0; j < 8; ++j) acc[i][j] = 0.0f;
    const int am = tid >> 1, ak = (tid & 1) * 4;
    const int bk = tid >> 5, bn = (tid & 31) * 4;
    const float* Aptr = A + (long)(row0 + am) * K + ak;
    const float* Bptr = Bm + (long)bk * N + col0 + bn;
    for (int kt = 0; kt < K; kt += BK) {
        float4 av = *(const float4*)(Aptr + kt);
        float4 bv = *(const float4*)(Bptr + (long)kt * N);
        As[ak + 0][am] = av.x; As[ak + 1][am] = av.y;
        As[ak + 2][am] = av.z; As[ak + 3][am] = av.w;
        *(float4*)&Bs[bk][bn] = bv;
        __syncthreads();
#pragma unroll
        for (int k = 0; k < BK; ++k) {
            float4 a0 = *(const float4*)&As[k][ty * 4];
            float4 a1 = *(const float4*)&As[k][64 + ty * 4];
            float4 b0 = *(const float4*)&Bs[k][tx * 4];
            float4 b1 = *(const float4*)&Bs[k][64 + tx * 4];
            float a[8] = {a0.x, a0.y, a0.z, a0.w, a1.x, a1.y, a1.z, a1.w};
            float b[8] = {b0.x, b0.y, b0.z, b0.w, b1.x, b1.y, b1.z, b1.w};
#pragma unroll
            for (int i = 0; i < 8; ++i)
#pragma unroll
                for (int j = 0; j < 8; ++j)
                    acc[i][j] = fmaf(a[i], b[j], acc[i][j]);
        }
        __syncthreads();
    }
    float bb[8];
#pragma unroll
    for (int j = 0; j < 4; ++j) {
        bb[j] = bias[col0 + tx * 4 + j];
        bb[j + 4] = bias[col0 + 64 + tx * 4 + j];
    }
#pragma unroll
    for (int i = 0; i < 8; ++i) {
        const int r = (i < 4) ? (ty * 4 + i) : (64 + ty * 4 + (i - 4));
        float* crow = C + (long)(row0 + r) * N + col0;
        float4 v0 = {acc[i][0] + bb[0], acc[i][1] + bb[1], acc[i][2] + bb[2], acc[i][3] + bb[3]};
        float4 v1 = {acc[i][4] + bb[4], acc[i][5] + bb[5], acc[i][6] + bb[6], acc[i][7] + bb[7]};
        *(float4*)(crow + tx * 4) = v0;
        *(float4*)(crow + 64 + tx * 4) = v1;
    }
}

// ------------------------------------------------------------ scan
// one thread per (b,u); batched loads -> register compute chain -> batched stores
#define SCAN_UNROLL 32

__global__ __launch_bounds__(256) void indrnn_scan(
    float* __restrict__ out, const float* __restrict__ h0,
    const float* __restrict__ u, int B, int T, int U)
{
    const int idx = blockIdx.x * blockDim.x + threadIdx.x;
    if (idx >= B * U) return;
    const int b = idx / U;
    const int un = idx - b * U;

    const float uc = fminf(fmaxf(u[un], 0.0f), 1.0f);
    float h = h0[(long)b * U + un];
    float* p = out + (long)b * T * U + un;

    for (int t = 0; t < T; t += SCAN_UNROLL) {
        float pv[SCAN_UNROLL];
#pragma unroll
        for (int i = 0; i < SCAN_UNROLL; ++i)
            pv[i] = p[(long)(t + i) * U];
#pragma unroll
        for (int i = 0; i < SCAN_UNROLL; ++i) {
            h = fmaxf(fmaf(h, uc, pv[i]), 0.0f);
            pv[i] = h;
        }
#pragma unroll
        for (int i = 0; i < SCAN_UNROLL; ++i)
            p[(long)(t + i) * U] = pv[i];
    }
}

// ------------------------------------------------------------ launch
extern "C" void kernel_launch(void* const* d_in, const int* in_sizes, int n_in,
                              void* d_out, int out_size, void* d_ws, size_t ws_size,
                              hipStream_t stream) {
    const float* x  = (const float*)d_in[0]; // [B,T,D]
    const float* h0 = (const float*)d_in[1]; // [B,U]
    const float* W  = (const float*)d_in[2]; // [D,U]
    const float* u  = (const float*)d_in[3]; // [U]
    const float* b  = (const float*)d_in[4]; // [U]
    float* out = (float*)d_out;              // [B,T,U]

    const int U = in_sizes[3];
    const int B = in_sizes[1] / U;
    const int D = in_sizes[2] / U;
    const int T = in_sizes[0] / (B * D);
    const int M = B * T;

    const size_t xb_bytes = (size_t)M * D * sizeof(unsigned short);
    const size_t wt_bytes = (size_t)U * D * sizeof(unsigned short);
    const bool use_mfma = (ws_size >= xb_bytes + wt_bytes) &&
                          (M % GBM == 0) && (U % GBN == 0) && (D % GBK == 0);

    if (use_mfma) {
        unsigned short* xb = (unsigned short*)d_ws;
        unsigned short* wt = (unsigned short*)((char*)d_ws + xb_bytes);

        const int n4 = (M * D) / 4;
        conv_x<<<(n4 + 255) / 256, 256, 0, stream>>>(x, xb, n4);

        const int nwt = U * (D / 4);
        conv_wt<<<(nwt + 255) / 256, 256, 0, stream>>>(W, wt, D, U);

        dim3 ggrid(M / GBM, U / GBN);
        gemm_mfma<<<ggrid, 256, 0, stream>>>(xb, wt, b, out, M, U, D);
    } else {
        dim3 ggrid(M / BM, U / BN);
        indrnn_gemm_bias<<<ggrid, 256, 0, stream>>>(x, W, b, out, M, U, D);
    }

    const int nthreads = B * U;
    indrnn_scan<<<(nthreads + 255) / 256, 256, 0, stream>>>(out, h0, u, B, T, U);
}

// Round 3
// 121.086 us; speedup vs baseline: 1.9402x; 1.1426x over previous
//
#include <hip/hip_runtime.h>

// IndRNN forward: proj = x @ W + b  (M=B*T, K=D=256, N=U), then
// h_t = relu(proj_t + h_{t-1} * clip(u,0,1)) over T.
// R2: single fused kernel per (b, 128-unit slice): stage x-chunk (64 t) to LDS
//     via global_load_lds w=16 (XOR-swizzled), MFMA with W-frags resident in
//     VGPRs (loaded once from global), proj written back into the same LDS
//     buffer, scan by waves 0-1 overlapped with async staging by waves 2-3.
//     Kills the 134 MB proj HBM round-trip of R1.

__device__ __forceinline__ unsigned short f2bf(float f) {
    unsigned int u = __float_as_uint(f);
    unsigned int r = (u + 0x7FFF + ((u >> 16) & 1)) >> 16;  // RNE
    return (unsigned short)r;
}

typedef __bf16 bf16x8 __attribute__((ext_vector_type(8)));
typedef float f32x4 __attribute__((ext_vector_type(4)));

typedef const unsigned char __attribute__((address_space(1))) gc_t;
typedef unsigned char __attribute__((address_space(3))) lds_t;

__device__ __forceinline__ void gl_lds16(const void* g, void* l) {
    __builtin_amdgcn_global_load_lds((gc_t*)g, (lds_t*)l, 16, 0, 0);
}

// ------------------------------------------------------------ conversion
__global__ __launch_bounds__(256) void conv_x(
    const float* __restrict__ x, unsigned short* __restrict__ xb, int n4)
{
    int i = blockIdx.x * blockDim.x + threadIdx.x;
    if (i >= n4) return;
    float4 v = *(const float4*)(x + (long)i * 4);
    ushort4 o;
    o.x = f2bf(v.x); o.y = f2bf(v.y); o.z = f2bf(v.z); o.w = f2bf(v.w);
    *(ushort4*)(xb + (long)i * 4) = o;
}

__global__ __launch_bounds__(256) void conv_wt(
    const float* __restrict__ W, unsigned short* __restrict__ Wt, int K, int N)
{
    int idx = blockIdx.x * blockDim.x + threadIdx.x;
    int kq = K >> 2;
    if (idx >= N * kq) return;
    int n = idx / kq;
    int k4 = (idx - n * kq) * 4;
    ushort4 o;
    o.x = f2bf(W[(long)(k4 + 0) * N + n]);
    o.y = f2bf(W[(long)(k4 + 1) * N + n]);
    o.z = f2bf(W[(long)(k4 + 2) * N + n]);
    o.w = f2bf(W[(long)(k4 + 3) * N + n]);
    *(ushort4*)(Wt + (long)n * K + k4) = o;
}

// ------------------------------------------------------------ fused kernel
// Requires D == 256, U % 128 == 0, T % 64 == 0.
#define TC 64    // timesteps per chunk
#define GN 128   // units per block

__global__ __launch_bounds__(256, 1) void indrnn_fused(
    const unsigned short* __restrict__ xb,   // bf16 [B*T, 256]
    const unsigned short* __restrict__ wt,   // bf16 [U, 256]  (W^T)
    const float* __restrict__ bias,          // [U]
    const float* __restrict__ h0,            // [B, U]
    const float* __restrict__ uvec,          // [U]
    float* __restrict__ out,                 // [B, T, U]
    int B, int T, int U)
{
    __shared__ char X[2][TC * 512];          // 2 x 32 KB: bf16 A-chunk, then fp32 proj

    const int tid  = threadIdx.x;
    const int lane = tid & 63;
    const int w    = tid >> 6;     // wave 0..3
    const int m    = lane & 15;
    const int quad = lane >> 4;    // 0..3
    const int b    = blockIdx.x;
    const int n0   = blockIdx.y * GN;
    const int tq   = (w >> 1) * 32;   // wave's row quadrant (t-local)
    const int cq   = (w & 1) * 64;    // wave's col quadrant

    // W fragments resident in registers: 4 col-tiles x 8 k-steps x 16B = 128 VGPRs.
    // B-frag layout (proven in R1): n = tile + m, k = kt*32 + quad*8 + e.
    bf16x8 bfr[4][8];
#pragma unroll
    for (int j = 0; j < 4; ++j)
#pragma unroll
        for (int kt = 0; kt < 8; ++kt)
            bfr[j][kt] = *(const bf16x8*)(
                wt + (long)(n0 + cq + j * 16 + m) * 256 + kt * 32 + quad * 8);

    float bb[4];
#pragma unroll
    for (int j = 0; j < 4; ++j) bb[j] = bias[n0 + cq + j * 16 + m];

    float uc = 0.0f, h = 0.0f;
    if (tid < GN) {
        uc = fminf(fmaxf(uvec[n0 + tid], 0.0f), 1.0f);
        h  = h0[(long)b * U + n0 + tid];
    }

    const unsigned short* xrow = xb + (long)b * T * 256;

    // ---- prologue: stage chunk 0 (all 4 waves, 8 x 1KB calls each).
    // LDS[row][p] <- global chunk (p ^ (row&15))  [16B chunks, 32/row]
    {
        const int p = lane & 31, hh = lane >> 5;
#pragma unroll
        for (int i = 0; i < 8; ++i) {
            int blk = i * 4 + w;          // 1KB block = 2 rows
            int row = blk * 2 + hh;
            int gp  = p ^ (row & 15);
            gl_lds16(xrow + (long)row * 256 + gp * 8, &X[0][blk * 1024]);
        }
    }

    const int nch = T / TC;
    for (int c = 0; c < nch; ++c) {
        char* Xc = X[c & 1];
        __syncthreads();   // staging of chunk c complete (barrier drains vmcnt)

        // ---- MFMA: wave computes 32t x 64u quadrant; A from LDS, B from regs
        f32x4 acc[2][4];
#pragma unroll
        for (int i = 0; i < 2; ++i)
#pragma unroll
            for (int j = 0; j < 4; ++j) acc[i][j] = (f32x4){0.f, 0.f, 0.f, 0.f};

#pragma unroll
        for (int kt = 0; kt < 8; ++kt) {
            const int off = (((kt * 4 + quad) ^ m) * 16);
            bf16x8 a0 = *(const bf16x8*)(Xc + (tq + m) * 512 + off);
            bf16x8 a1 = *(const bf16x8*)(Xc + (tq + 16 + m) * 512 + off);
#pragma unroll
            for (int j = 0; j < 4; ++j) {
                acc[0][j] = __builtin_amdgcn_mfma_f32_16x16x32_bf16(
                    a0, bfr[j][kt], acc[0][j], 0, 0, 0);
                acc[1][j] = __builtin_amdgcn_mfma_f32_16x16x32_bf16(
                    a1, bfr[j][kt], acc[1][j], 0, 0, 0);
            }
        }
        __syncthreads();   // all reads of Xc done

        // ---- proj (+bias) -> same LDS buffer, fp32, col-swizzled by quad
        float* pf = (float*)Xc;
#pragma unroll
        for (int i = 0; i < 2; ++i)
#pragma unroll
            for (int j = 0; j < 4; ++j)
#pragma unroll
                for (int r = 0; r < 4; ++r) {
                    int tl  = tq + i * 16 + quad * 4 + r;
                    int col = cq + j * 16 + m;
                    int cs  = col ^ (quad << 4);   // quad == (tl>>2)&3
                    pf[tl * GN + cs] = acc[i][j][r] + bb[j];
                }
        __syncthreads();   // proj visible

        // ---- waves 2-3: async-stage chunk c+1; waves 0-1: scan chunk c
        if (tid >= 128) {
            if (c + 1 < nch) {
                char* Xn = X[(c + 1) & 1];
                const unsigned short* gb = xrow + (long)(c + 1) * TC * 256;
                const int p = lane & 31, hh = lane >> 5;
#pragma unroll
                for (int i = 0; i < 16; ++i) {
                    int blk = i * 2 + (w - 2);
                    int row = blk * 2 + hh;
                    int gp  = p ^ (row & 15);
                    gl_lds16(gb + (long)row * 256 + gp * 8, Xn + blk * 1024);
                }
            }
        } else {
            const float* pfr = (const float*)Xc;
            float* og = out + ((long)b * T + c * TC) * U + n0 + tid;
#pragma unroll 8
            for (int t = 0; t < TC; ++t) {
                float pv = pfr[t * GN + (tid ^ (((t >> 2) & 3) << 4))];
                h = fmaxf(fmaf(h, uc, pv), 0.0f);
                og[(long)t * U] = h;
            }
        }
    }
}

// ------------------------------------------------------------ fp32 fallback
#define BM 128
#define BN 128
#define BK 8

__global__ __launch_bounds__(256) void indrnn_gemm_bias(
    const float* __restrict__ A, const float* __restrict__ Bm,
    const float* __restrict__ bias, float* __restrict__ C,
    int M, int N, int K)
{
    __shared__ float As[BK][BM];
    __shared__ float Bs[BK][BN];
    const int tid = threadIdx.x;
    const int row0 = blockIdx.x * BM, col0 = blockIdx.y * BN;
    const int tx = tid & 15, ty = tid >> 4;
    float acc[8][8];
#pragma unroll
    for (int i = 0; i < 8; ++i)
#pragma unroll
        for (int j = 0; j < 8; ++j) acc[i][j] = 0.0f;
    const int am = tid >> 1, ak = (tid & 1) * 4;
    const int bk = tid >> 5, bn = (tid & 31) * 4;
    const float* Aptr = A + (long)(row0 + am) * K + ak;
    const float* Bptr = Bm + (long)bk * N + col0 + bn;
    for (int kt = 0; kt < K; kt += BK) {
        float4 av = *(const float4*)(Aptr + kt);
        float4 bv = *(const float4*)(Bptr + (long)kt * N);
        As[ak + 0][am] = av.x; As[ak + 1][am] = av.y;
        As[ak + 2][am] = av.z; As[ak + 3][am] = av.w;
        *(float4*)&Bs[bk][bn] = bv;
        __syncthreads();
#pragma unroll
        for (int k = 0; k < BK; ++k) {
            float4 a0 = *(const float4*)&As[k][ty * 4];
            float4 a1 = *(const float4*)&As[k][64 + ty * 4];
            float4 b0 = *(const float4*)&Bs[k][tx * 4];
            float4 b1 = *(const float4*)&Bs[k][64 + tx * 4];
            float a[8] = {a0.x, a0.y, a0.z, a0.w, a1.x, a1.y, a1.z, a1.w};
            float bb2[8] = {b0.x, b0.y, b0.z, b0.w, b1.x, b1.y, b1.z, b1.w};
#pragma unroll
            for (int i = 0; i < 8; ++i)
#pragma unroll
                for (int j = 0; j < 8; ++j)
                    acc[i][j] = fmaf(a[i], bb2[j], acc[i][j]);
        }
        __syncthreads();
    }
    float bb[8];
#pragma unroll
    for (int j = 0; j < 4; ++j) {
        bb[j] = bias[col0 + tx * 4 + j];
        bb[j + 4] = bias[col0 + 64 + tx * 4 + j];
    }
#pragma unroll
    for (int i = 0; i < 8; ++i) {
        const int r = (i < 4) ? (ty * 4 + i) : (64 + ty * 4 + (i - 4));
        float* crow = C + (long)(row0 + r) * N + col0;
        float4 v0 = {acc[i][0] + bb[0], acc[i][1] + bb[1], acc[i][2] + bb[2], acc[i][3] + bb[3]};
        float4 v1 = {acc[i][4] + bb[4], acc[i][5] + bb[5], acc[i][6] + bb[6], acc[i][7] + bb[7]};
        *(float4*)(crow + tx * 4) = v0;
        *(float4*)(crow + 64 + tx * 4) = v1;
    }
}

#define SCAN_UNROLL 32

__global__ __launch_bounds__(256) void indrnn_scan(
    float* __restrict__ out, const float* __restrict__ h0,
    const float* __restrict__ u, int B, int T, int U)
{
    const int idx = blockIdx.x * blockDim.x + threadIdx.x;
    if (idx >= B * U) return;
    const int b = idx / U;
    const int un = idx - b * U;
    const float uc = fminf(fmaxf(u[un], 0.0f), 1.0f);
    float h = h0[(long)b * U + un];
    float* p = out + (long)b * T * U + un;
    for (int t = 0; t < T; t += SCAN_UNROLL) {
        float pv[SCAN_UNROLL];
#pragma unroll
        for (int i = 0; i < SCAN_UNROLL; ++i)
            pv[i] = p[(long)(t + i) * U];
#pragma unroll
        for (int i = 0; i < SCAN_UNROLL; ++i) {
            h = fmaxf(fmaf(h, uc, pv[i]), 0.0f);
            pv[i] = h;
        }
#pragma unroll
        for (int i = 0; i < SCAN_UNROLL; ++i)
            p[(long)(t + i) * U] = pv[i];
    }
}

// ------------------------------------------------------------ launch
extern "C" void kernel_launch(void* const* d_in, const int* in_sizes, int n_in,
                              void* d_out, int out_size, void* d_ws, size_t ws_size,
                              hipStream_t stream) {
    const float* x  = (const float*)d_in[0]; // [B,T,D]
    const float* h0 = (const float*)d_in[1]; // [B,U]
    const float* W  = (const float*)d_in[2]; // [D,U]
    const float* u  = (const float*)d_in[3]; // [U]
    const float* b  = (const float*)d_in[4]; // [U]
    float* out = (float*)d_out;              // [B,T,U]

    const int U = in_sizes[3];
    const int B = in_sizes[1] / U;
    const int D = in_sizes[2] / U;
    const int T = in_sizes[0] / (B * D);
    const int M = B * T;

    const size_t xb_bytes = (size_t)M * D * sizeof(unsigned short);
    const size_t wt_bytes = (size_t)U * D * sizeof(unsigned short);
    const bool fused_ok = (D == 256) && (U % GN == 0) && (T % TC == 0) &&
                          (ws_size >= xb_bytes + wt_bytes);

    if (fused_ok) {
        unsigned short* xb = (unsigned short*)d_ws;
        unsigned short* wt = (unsigned short*)((char*)d_ws + xb_bytes);

        const int n4 = (M * D) / 4;
        conv_x<<<(n4 + 255) / 256, 256, 0, stream>>>(x, xb, n4);
        const int nwt = U * (D / 4);
        conv_wt<<<(nwt + 255) / 256, 256, 0, stream>>>(W, wt, D, U);

        dim3 g(B, U / GN);
        indrnn_fused<<<g, 256, 0, stream>>>(xb, wt, b, h0, u, out, B, T, U);
    } else {
        dim3 ggrid(M / BM, U / BN);
        indrnn_gemm_bias<<<ggrid, 256, 0, stream>>>(x, W, b, out, M, U, D);
        const int nthreads = B * U;
        indrnn_scan<<<(nthreads + 255) / 256, 256, 0, stream>>>(out, h0, u, B, T, U);
    }
}